// Round 1
// 341.614 us; speedup vs baseline: 1.0278x; 1.0278x over previous
//
#include <hip/hip_runtime.h>

#define HH 200
#define WW 196
#define CC 256
#define NCAMS 6
#define NPTS (HH * WW)          // 39200
#define NP4  (NPTS / 4)         // 9800 point-groups per cam (NPTS % 4 == 0)
#define NGRP (NP4 * NCAMS)      // 58800 total thread work items
#define SSZ 400
#define NCELLS (SSZ * SSZ)      // 160000
#define TPB 256

// Fused kernel: each thread owns 4 consecutive plane points of one cam.
// float4 feats loads (16 B/lane, coalesced 1 KB/wave/instr), 4 independent
// FMA chains, then per-point transform + run-merged atomic scatter.
__global__ __launch_bounds__(TPB)
void pon_scatter_kernel(const float* __restrict__ feats,      // (6, 256, 196, 200)
                        const float* __restrict__ cam2ego,    // (6, 4, 4)
                        const float* __restrict__ lcoords,    // (4, 39200)
                        const unsigned char* __restrict__ mask_raw, // (200,196), elem width unknown
                        const float* __restrict__ w_cls,      // (256,)
                        float* __restrict__ sums,             // (160000,)
                        float* __restrict__ cnt)              // (160000,)
{
    __shared__ float w_s[CC];
    __shared__ int mask_wide_s;   // 1 => 4 bytes/elem, 0 => 1 byte/elem

    const int tid = threadIdx.x;
    w_s[tid] = w_cls[tid];        // blockDim.x == 256 == CC

    // Wave-parallel mask element-width detection. Same 64-word sample and
    // same decision rule as the verified serial version: a 1-byte (~90% true)
    // layout packs words like 0x01010101 which are never in {0,1,0x3f800000}.
    if (tid < 64) {
        const unsigned int v = ((const unsigned int*)mask_raw)[tid];
        const int ok = (v == 0u) | (v == 1u) | (v == 0x3f800000u);
        const int wide = __all(ok);
        if (tid == 0) mask_wide_s = wide;
    }
    __syncthreads();

    const int g = blockIdx.x * TPB + tid;
    if (g >= NGRP) return;

    const bool mask_wide = (mask_wide_s != 0);
    const int cam = g / NP4;
    const int p0  = (g - cam * NP4) * 4;   // first of 4 consecutive plane points

    // ---- 256-channel dot products for 4 points, float4-vectorized ----
    // f4[ch * NP4] is feats[cam][ch][p0..p0+3] (16 B aligned: p0 % 4 == 0).
    const float4* __restrict__ f4 =
        (const float4*)(feats + (size_t)cam * CC * NPTS) + (p0 >> 2);
    const float4* __restrict__ w_s4 = (const float4*)w_s;

    float a0 = 0.0f, a1 = 0.0f, a2 = 0.0f, a3 = 0.0f;
    #pragma unroll 4
    for (int ch4 = 0; ch4 < CC / 4; ++ch4) {
        const float4 wv = w_s4[ch4];        // one ds_read_b128 per 4 channels
        const float4 v0 = f4[(size_t)(4 * ch4 + 0) * NP4];
        const float4 v1 = f4[(size_t)(4 * ch4 + 1) * NP4];
        const float4 v2 = f4[(size_t)(4 * ch4 + 2) * NP4];
        const float4 v3 = f4[(size_t)(4 * ch4 + 3) * NP4];
        // Per-point channel order is ascending, identical to the verified
        // scalar kernel: acc = fma(w[ch], f[ch], acc) for ch = 0..255.
        a0 = fmaf(wv.x, v0.x, a0); a1 = fmaf(wv.x, v0.y, a1);
        a2 = fmaf(wv.x, v0.z, a2); a3 = fmaf(wv.x, v0.w, a3);
        a0 = fmaf(wv.y, v1.x, a0); a1 = fmaf(wv.y, v1.y, a1);
        a2 = fmaf(wv.y, v1.z, a2); a3 = fmaf(wv.y, v1.w, a3);
        a0 = fmaf(wv.z, v2.x, a0); a1 = fmaf(wv.z, v2.y, a1);
        a2 = fmaf(wv.z, v2.z, a2); a3 = fmaf(wv.z, v2.w, a3);
        a0 = fmaf(wv.w, v3.x, a0); a1 = fmaf(wv.w, v3.y, a1);
        a2 = fmaf(wv.w, v3.z, a2); a3 = fmaf(wv.w, v3.w, a3);
    }
    const float accv[4] = {a0, a1, a2, a3};

    // ---- coordinate transform (bit-exact vs numpy reference) ----
    const float* M = cam2ego + cam * 16;
    const float m00 = M[0], m01 = M[1], m03 = M[3];
    const float m10 = M[4], m11 = M[5], m13 = M[7];

    // p0 % 4 == 0 and HH % 4 == 0 => the 4 points share w and h never wraps.
    const int h0 = p0 % HH;
    const int w0 = p0 / HH;

    // Run-merged atomic scatter: consecutive h-points usually share a cell
    // (grid spacing ~0.25 m vs 0.5 m cells) — merge before hitting TCC.
    int   pcell = -1;
    float psum = 0.0f, pcnt = 0.0f;
    #pragma unroll
    for (int k = 0; k < 4; ++k) {
        const int n = (h0 + k) * WW + w0;      // reference's flat point index
        const float x = lcoords[n];            // row 0: x
        const float y = lcoords[NPTS + n];     // row 1: y
        // Strict IEEE mul/add, j-ascending, mirrors np.einsum:
        // ((m00*x + m01*y) + m02*0) + m03*1
        const float ex = __fadd_rn(__fadd_rn(__fmul_rn(m00, x), __fmul_rn(m01, y)), m03);
        const float ey = __fadd_rn(__fadd_rn(__fmul_rn(m10, x), __fmul_rn(m11, y)), m13);
        // (c + 100) / 0.5 == (c + 100) * 2 (exact); jnp.round == rintf
        const int i0 = (int)rintf(__fmul_rn(__fadd_rn(ex, 100.0f), 2.0f));
        const int i1 = (int)rintf(__fmul_rn(__fadd_rn(ey, 100.0f), 2.0f));

        bool m;
        if (mask_wide) m = (((const unsigned int*)mask_raw)[n] != 0u);
        else           m = (mask_raw[n] != 0);

        const bool valid = m & (i0 >= 0) & (i0 < SSZ) & (i1 >= 0) & (i1 < SSZ);
        if (valid) {
            const int cell = i0 * SSZ + i1;
            if (cell == pcell) { psum += accv[k]; pcnt += 1.0f; }
            else {
                if (pcell >= 0) { atomicAdd(&sums[pcell], psum); atomicAdd(&cnt[pcell], pcnt); }
                pcell = cell; psum = accv[k]; pcnt = 1.0f;
            }
        }
    }
    if (pcell >= 0) { atomicAdd(&sums[pcell], psum); atomicAdd(&cnt[pcell], pcnt); }
}

__global__ __launch_bounds__(256)
void pon_finalize_kernel(const float4* __restrict__ sums4,
                         const float4* __restrict__ cnt4,
                         const float* __restrict__ b_cls,
                         float4* __restrict__ out4)
{
    const int c = blockIdx.x * blockDim.x + threadIdx.x;
    if (c < NCELLS / 4) {
        const float b = b_cls[0];
        const float4 s = sums4[c];
        const float4 k = cnt4[c];
        float4 o;
        // cnt==0 cells have sums==0 exactly (only valid points scatter),
        // so out = 0 + b there — matches reference's where().
        o.x = ((k.x >= 1.0f) ? s.x / k.x : 0.0f) + b;
        o.y = ((k.y >= 1.0f) ? s.y / k.y : 0.0f) + b;
        o.z = ((k.z >= 1.0f) ? s.z / k.z : 0.0f) + b;
        o.w = ((k.w >= 1.0f) ? s.w / k.w : 0.0f) + b;
        out4[c] = o;
    }
}

extern "C" void kernel_launch(void* const* d_in, const int* in_sizes, int n_in,
                              void* d_out, int out_size, void* d_ws, size_t ws_size,
                              hipStream_t stream) {
    const float* td_feats  = (const float*)d_in[0];
    const float* cam2ego   = (const float*)d_in[1];
    const float* lcoords   = (const float*)d_in[2];
    const unsigned char* mask = (const unsigned char*)d_in[3];
    const float* w_cls     = (const float*)d_in[4];
    const float* b_cls     = (const float*)d_in[5];
    float* out = (float*)d_out;

    float* sums = (float*)d_ws;
    float* cnt  = sums + NCELLS;

    // d_ws is re-poisoned to 0xAA before every launch — zero the accumulators.
    hipMemsetAsync(d_ws, 0, (size_t)2 * NCELLS * sizeof(float), stream);

    dim3 block(TPB);
    dim3 grid((NGRP + TPB - 1) / TPB);    // 230 blocks, flat (cam, point4) space
    pon_scatter_kernel<<<grid, block, 0, stream>>>(
        td_feats, cam2ego, lcoords, mask, w_cls, sums, cnt);

    pon_finalize_kernel<<<(NCELLS / 4 + 255) / 256, 256, 0, stream>>>(
        (const float4*)sums, (const float4*)cnt, b_cls, (float4*)out);
}